// Round 1
// baseline (421.652 us; speedup 1.0000x reference)
//
#include <hip/hip_runtime.h>

#define NN 32768      // nodes
#define NE 131072     // edges
#define HH 4          // heads

constexpr float kLrelu = 0.2f;

// ---------------------------------------------------------------------------
// Tiled fp32 GEMM: C[N,OUT] = A[N,K] @ W[K,OUT] (+bias). 32x32 tile, 256 thr.
// CONCAT: feature k<SPLIT from A (row stride SPLIT), else A2 (stride K-SPLIT).
// ---------------------------------------------------------------------------
template<int K, int OUT, bool CONCAT, int SPLIT>
__global__ __launch_bounds__(256) void gemm_kernel(
    const float* __restrict__ A, const float* __restrict__ A2,
    const float* __restrict__ W, const float* __restrict__ bias,
    float* __restrict__ C)
{
    __shared__ float As[32][K];
    __shared__ float Bs[K][32];
    const int row0 = blockIdx.x * 32;
    const int col0 = blockIdx.y * 32;
    const int tid  = threadIdx.x;

    for (int idx = tid; idx < 32 * K; idx += 256) {
        int r = idx / K, k = idx - r * K;
        float v;
        if (CONCAT) {
            v = (k < SPLIT) ? A [(size_t)(row0 + r) * SPLIT + k]
                            : A2[(size_t)(row0 + r) * (K - SPLIT) + (k - SPLIT)];
        } else {
            v = A[(size_t)(row0 + r) * K + k];
        }
        As[r][k] = v;
    }
    for (int idx = tid; idx < K * 32; idx += 256) {
        int k = idx >> 5, c = idx & 31;
        Bs[k][c] = W[(size_t)k * OUT + col0 + c];
    }
    __syncthreads();

    const int c  = tid & 31;
    const int rb = tid >> 5;           // 0..7
    float acc0 = 0.f, acc1 = 0.f, acc2 = 0.f, acc3 = 0.f;
    #pragma unroll 4
    for (int k = 0; k < K; ++k) {
        float b = Bs[k][c];
        acc0 += As[rb     ][k] * b;
        acc1 += As[rb +  8][k] * b;
        acc2 += As[rb + 16][k] * b;
        acc3 += As[rb + 24][k] * b;
    }
    float bv = bias ? bias[col0 + c] : 0.0f;
    C[(size_t)(row0 + rb     ) * OUT + col0 + c] = acc0 + bv;
    C[(size_t)(row0 + rb +  8) * OUT + col0 + c] = acc1 + bv;
    C[(size_t)(row0 + rb + 16) * OUT + col0 + c] = acc2 + bv;
    C[(size_t)(row0 + rb + 24) * OUT + col0 + c] = acc3 + bv;
}

// ---------------------------------------------------------------------------
// Per-node attention scores: s_src[n,h] = sum_f proj[n,h,f]*a_src[h,f], same trg
// ---------------------------------------------------------------------------
template<int F>
__global__ __launch_bounds__(256) void scores_kernel(
    const float* __restrict__ proj,
    const float* __restrict__ a_src, const float* __restrict__ a_trg,
    float* __restrict__ s_src, float* __restrict__ s_trg)
{
    int t = blockIdx.x * 256 + threadIdx.x;      // n*H + h
    if (t >= NN * HH) return;
    int n = t >> 2, h = t & 3;
    const float* p  = proj  + (size_t)n * (HH * F) + h * F;
    const float* as = a_src + h * F;
    const float* at = a_trg + h * F;
    float ss = 0.f, st = 0.f;
    #pragma unroll 4
    for (int f = 0; f < F; ++f) {
        float v = p[f];
        ss += v * as[f];
        st += v * at[f];
    }
    s_src[t] = ss;
    s_trg[t] = st;
}

// ---------------------------------------------------------------------------
// Per-edge: score = lrelu(s_src[src]+s_trg[trg]); ex = exp(score);
// denom[grp] += ex (grp = src or trg). No max-shift (cancels; see analysis).
// ---------------------------------------------------------------------------
__global__ __launch_bounds__(256) void edge_kernel(
    const int* __restrict__ ei,
    const float* __restrict__ s_src, const float* __restrict__ s_trg,
    float* __restrict__ ex, float* __restrict__ denom, int softmax_on_src)
{
    int e = blockIdx.x * 256 + threadIdx.x;
    if (e >= NE) return;
    int s = ei[e], t = ei[NE + e];
    const float4 ss = *(const float4*)(s_src + 4 * (size_t)s);
    const float4 st = *(const float4*)(s_trg + 4 * (size_t)t);
    int g = softmax_on_src ? s : t;
    float sc[4] = { ss.x + st.x, ss.y + st.y, ss.z + st.z, ss.w + st.w };
    float ev[4];
    #pragma unroll
    for (int h = 0; h < 4; ++h) {
        float x  = sc[h];
        float lr = x > 0.f ? x : kLrelu * x;
        ev[h] = expf(lr);
        atomicAdd(&denom[4 * (size_t)g + h], ev[h]);
    }
    *(float4*)(ex + 4 * (size_t)e) = make_float4(ev[0], ev[1], ev[2], ev[3]);
}

// ---------------------------------------------------------------------------
// Aggregation: agg[trg,f] += sum_h proj[src,h,f] * ex[e,h]/(denom[grp,h]+eps)
// Heads summed in registers -> ONE atomic per (edge,f).
// blockDim = EPB*F threads; EPB edges per block.
// ---------------------------------------------------------------------------
template<int F, int EPB>
__global__ __launch_bounds__(EPB * F) void aggregate_kernel(
    const int* __restrict__ ei,
    const float* __restrict__ proj,
    const float* __restrict__ ex, const float* __restrict__ denom,
    float* __restrict__ agg, int softmax_on_src)
{
    int tid = threadIdx.x;
    int le  = tid / F, f = tid - le * F;
    int e   = blockIdx.x * EPB + le;
    if (e >= NE) return;
    int s = ei[e], t = ei[NE + e];
    int g = softmax_on_src ? s : t;
    const float4 ev = *(const float4*)(ex    + 4 * (size_t)e);
    const float4 dv = *(const float4*)(denom + 4 * (size_t)g);
    float a0 = ev.x / (dv.x + 1e-16f);
    float a1 = ev.y / (dv.y + 1e-16f);
    float a2 = ev.z / (dv.z + 1e-16f);
    float a3 = ev.w / (dv.w + 1e-16f);
    const float* p = proj + (size_t)s * (4 * F) + f;
    float val = p[0] * a0 + p[F] * a1 + p[2 * F] * a2 + p[3 * F] * a3;
    atomicAdd(&agg[(size_t)t * F + f], val);
}

// ---------------------------------------------------------------------------
// Finalize: agg = agg/H + x_p + bias   (mean over heads + skip + bias)
// ---------------------------------------------------------------------------
template<int F>
__global__ __launch_bounds__(256) void finalize_kernel(
    float* __restrict__ agg, const float* __restrict__ x_p,
    const float* __restrict__ bias)
{
    int i = blockIdx.x * 256 + threadIdx.x;
    if (i >= NN * F) return;
    int f = i % F;
    agg[i] = agg[i] * 0.25f + x_p[i] + bias[f];
}

// ---------------------------------------------------------------------------
extern "C" void kernel_launch(void* const* d_in, const int* in_sizes, int n_in,
                              void* d_out, int out_size, void* d_ws, size_t ws_size,
                              hipStream_t stream)
{
    const float* rna   = (const float*)d_in[0];    // [N,128]
    const float* prot  = (const float*)d_in[1];    // [N,32]
    const int*   ei    = (const int*)  d_in[2];    // [2,E]
    const float* Wgp   = (const float*)d_in[3];    // [128,64]
    const float* bgp   = (const float*)d_in[4];
    const float* Wgr   = (const float*)d_in[5];    // [64,128]
    const float* bgr   = (const float*)d_in[6];
    const float* Wg    = (const float*)d_in[7];    // [64,256]
    const float* ags   = (const float*)d_in[8];    // [4,64]
    const float* agt   = (const float*)d_in[9];
    const float* bg    = (const float*)d_in[10];   // [64]
    const float* Wcp   = (const float*)d_in[11];   // [160,96]
    const float* bcp   = (const float*)d_in[12];
    const float* Wcr   = (const float*)d_in[13];   // [96,160]
    const float* bcr   = (const float*)d_in[14];
    const float* Wc    = (const float*)d_in[15];   // [96,384]
    const float* acs   = (const float*)d_in[16];   // [4,96]
    const float* act   = (const float*)d_in[17];
    const float* bc    = (const float*)d_in[18];   // [96]

    float* out_gat   = (float*)d_out;              // [N,128]
    float* out_cross = out_gat + (size_t)NN * 128; // [N,160]

    float* ws   = (float*)d_ws;
    float* x_p  = ws;                         // N*96 (max of 64/96)
    float* proj = x_p  + (size_t)NN * 96;     // N*384 (max of 256/384)
    float* ssrc = proj + (size_t)NN * 384;    // N*4
    float* strg = ssrc + (size_t)NN * 4;      // N*4
    float* den  = strg + (size_t)NN * 4;      // N*4
    float* ex   = den  + (size_t)NN * 4;      // E*4
    float* agg  = ex   + (size_t)NE * 4;      // N*96

    // ======================= GAT path (F=64, softmax on trg) ================
    gemm_kernel<128, 64, false, 0><<<dim3(NN/32, 2), 256, 0, stream>>>(rna, nullptr, Wgp, bgp, x_p);
    gemm_kernel<64, 256, false, 0><<<dim3(NN/32, 8), 256, 0, stream>>>(x_p, nullptr, Wg, nullptr, proj);
    scores_kernel<64><<<(NN * HH) / 256, 256, 0, stream>>>(proj, ags, agt, ssrc, strg);
    hipMemsetAsync(den, 0, (size_t)NN * 4 * sizeof(float), stream);
    edge_kernel<<<NE / 256, 256, 0, stream>>>(ei, ssrc, strg, ex, den, 0);
    hipMemsetAsync(agg, 0, (size_t)NN * 64 * sizeof(float), stream);
    aggregate_kernel<64, 4><<<NE / 4, 256, 0, stream>>>(ei, proj, ex, den, agg, 0);
    finalize_kernel<64><<<(NN * 64) / 256, 256, 0, stream>>>(agg, x_p, bg);
    gemm_kernel<64, 128, false, 0><<<dim3(NN/32, 4), 256, 0, stream>>>(agg, nullptr, Wgr, bgr, out_gat);

    // ====================== Cross path (F=96, softmax on src) ===============
    gemm_kernel<160, 96, true, 128><<<dim3(NN/32, 3), 256, 0, stream>>>(rna, prot, Wcp, bcp, x_p);
    gemm_kernel<96, 384, false, 0><<<dim3(NN/32, 12), 256, 0, stream>>>(x_p, nullptr, Wc, nullptr, proj);
    scores_kernel<96><<<(NN * HH) / 256, 256, 0, stream>>>(proj, acs, act, ssrc, strg);
    hipMemsetAsync(den, 0, (size_t)NN * 4 * sizeof(float), stream);
    edge_kernel<<<NE / 256, 256, 0, stream>>>(ei, ssrc, strg, ex, den, 1);
    hipMemsetAsync(agg, 0, (size_t)NN * 96 * sizeof(float), stream);
    aggregate_kernel<96, 2><<<NE / 2, 192, 0, stream>>>(ei, proj, ex, den, agg, 1);
    finalize_kernel<96><<<(NN * 96) / 256, 256, 0, stream>>>(agg, x_p, bc);
    gemm_kernel<96, 160, false, 0><<<dim3(NN/32, 5), 256, 0, stream>>>(agg, nullptr, Wcr, bcr, out_cross);
}

// Round 2
// 279.123 us; speedup vs baseline: 1.5106x; 1.5106x over previous
//
#include <hip/hip_runtime.h>
#include <hip/hip_bf16.h>

#define NN 32768      // nodes
#define NE 131072     // edges
#define HH 4          // heads

constexpr float kLrelu = 0.2f;

using bf16x8 = __attribute__((ext_vector_type(8))) __bf16;
using f32x4  = __attribute__((ext_vector_type(4))) float;

__device__ inline short f2b(float f) {
    __hip_bfloat16 h = __float2bfloat16(f);          // RTNE
    return __builtin_bit_cast(short, h);
}
__device__ inline float b2f(short s) {
    __hip_bfloat16 h = __builtin_bit_cast(__hip_bfloat16, s);
    return __bfloat162float(h);
}

// ---------------------------------------------------------------------------
// bf16 MFMA GEMM: C[M,OUTN] = A[M,K](bf16, row stride LDA) @ Wt^T (+bias)
// Wt is [OUTN,K] bf16 (pre-transposed weight). Direct-from-global fragments:
//   a: A[row0+lane%16][k0+8*(lane/16)+i]   (contiguous 16B)
//   b: Wt[col0+lane%16][k0+8*(lane/16)+i]  (contiguous 16B)
//   d: row=(lane>>4)*4+j, col=lane&15      (m89-verified C/D layout)
// Block = 4 waves; wave w owns rows [w*32, w*32+32), block cols = 32.
// ---------------------------------------------------------------------------
template<int K, int LDA, int OUTN, bool BF16OUT>
__global__ __launch_bounds__(256) void mfma_gemm(
    const short* __restrict__ A, const short* __restrict__ Wt,
    const float* __restrict__ bias,
    float* __restrict__ Cf, short* __restrict__ Cb)
{
    const int wave = threadIdx.x >> 6;
    const int lane = threadIdx.x & 63;
    const int row0 = blockIdx.x * 128 + wave * 32;
    const int col0 = blockIdx.y * 32;
    const int lr   = lane & 15;
    const int kb   = lane >> 4;            // 0..3

    f32x4 acc[2][2] = {};
    const short* a0 = A  + (size_t)(row0 + lr) * LDA + 8 * kb;
    const short* a1 = a0 + 16 * LDA;
    const short* b0 = Wt + (size_t)(col0 + lr) * K + 8 * kb;
    const short* b1 = b0 + 16 * K;

    #pragma unroll
    for (int k0 = 0; k0 < K; k0 += 32) {
        bf16x8 af0 = *(const bf16x8*)(a0 + k0);
        bf16x8 af1 = *(const bf16x8*)(a1 + k0);
        bf16x8 bf0 = *(const bf16x8*)(b0 + k0);
        bf16x8 bf1 = *(const bf16x8*)(b1 + k0);
        acc[0][0] = __builtin_amdgcn_mfma_f32_16x16x32_bf16(af0, bf0, acc[0][0], 0, 0, 0);
        acc[0][1] = __builtin_amdgcn_mfma_f32_16x16x32_bf16(af0, bf1, acc[0][1], 0, 0, 0);
        acc[1][0] = __builtin_amdgcn_mfma_f32_16x16x32_bf16(af1, bf0, acc[1][0], 0, 0, 0);
        acc[1][1] = __builtin_amdgcn_mfma_f32_16x16x32_bf16(af1, bf1, acc[1][1], 0, 0, 0);
    }

    #pragma unroll
    for (int mf = 0; mf < 2; ++mf) {
        #pragma unroll
        for (int nf = 0; nf < 2; ++nf) {
            const int c  = col0 + nf * 16 + lr;
            const float bv = bias ? bias[c] : 0.0f;
            #pragma unroll
            for (int j = 0; j < 4; ++j) {
                const int r = row0 + mf * 16 + kb * 4 + j;
                const float v = acc[mf][nf][j] + bv;
                if constexpr (BF16OUT) Cb[(size_t)r * OUTN + c] = f2b(v);
                else                   Cf[(size_t)r * OUTN + c] = v;
            }
        }
    }
}

// ---------------------------------------------------------------------------
// Weight transpose + fp32 -> bf16: Wt[n*K+k] = bf16(W[k*N+n])
// ---------------------------------------------------------------------------
__global__ void wt_kernel(const float* __restrict__ W, short* __restrict__ Wt,
                          int K, int N)
{
    int t = blockIdx.x * 256 + threadIdx.x;
    if (t >= K * N) return;
    int n = t / K, k = t - n * K;
    Wt[t] = f2b(W[(size_t)k * N + n]);
}

// ---------------------------------------------------------------------------
// Build bf16 concat [N,160] = [rna | prot]; each thread converts 4 floats.
// ---------------------------------------------------------------------------
__global__ __launch_bounds__(256) void concat_kernel(
    const float* __restrict__ rna, const float* __restrict__ prot,
    short* __restrict__ cb)
{
    int t = blockIdx.x * 256 + threadIdx.x;
    if (t >= NN * 40) return;
    int n = t / 40, j = (t - n * 40) * 4;
    float4 v = (j < 128) ? *(const float4*)(rna  + (size_t)n * 128 + j)
                         : *(const float4*)(prot + (size_t)n * 32 + (j - 128));
    short4 o = { f2b(v.x), f2b(v.y), f2b(v.z), f2b(v.w) };
    *(short4*)(cb + (size_t)n * 160 + j) = o;
}

// ---------------------------------------------------------------------------
// Per-node attention scores from fp32 proj
// ---------------------------------------------------------------------------
template<int F>
__global__ __launch_bounds__(256) void scores_kernel(
    const float* __restrict__ proj,
    const float* __restrict__ a_src, const float* __restrict__ a_trg,
    float* __restrict__ s_src, float* __restrict__ s_trg)
{
    int t = blockIdx.x * 256 + threadIdx.x;      // n*H + h
    if (t >= NN * HH) return;
    int n = t >> 2, h = t & 3;
    const float* p  = proj  + (size_t)n * (HH * F) + h * F;
    const float* as = a_src + h * F;
    const float* at = a_trg + h * F;
    float ss = 0.f, st = 0.f;
    #pragma unroll 4
    for (int f = 0; f < F; ++f) {
        float v = p[f];
        ss += v * as[f];
        st += v * at[f];
    }
    s_src[t] = ss;
    s_trg[t] = st;
}

// ---------------------------------------------------------------------------
// Per-edge exp(lrelu(score)) + denom atomics (global-max shift cancels)
// ---------------------------------------------------------------------------
__global__ __launch_bounds__(256) void edge_kernel(
    const int* __restrict__ ei,
    const float* __restrict__ s_src, const float* __restrict__ s_trg,
    float* __restrict__ ex, float* __restrict__ denom, int softmax_on_src)
{
    int e = blockIdx.x * 256 + threadIdx.x;
    if (e >= NE) return;
    int s = ei[e], t = ei[NE + e];
    const float4 ss = *(const float4*)(s_src + 4 * (size_t)s);
    const float4 st = *(const float4*)(s_trg + 4 * (size_t)t);
    int g = softmax_on_src ? s : t;
    float sc[4] = { ss.x + st.x, ss.y + st.y, ss.z + st.z, ss.w + st.w };
    float ev[4];
    #pragma unroll
    for (int h = 0; h < 4; ++h) {
        float x  = sc[h];
        float lr = x > 0.f ? x : kLrelu * x;
        ev[h] = expf(lr);
        atomicAdd(&denom[4 * (size_t)g + h], ev[h]);
    }
    *(float4*)(ex + 4 * (size_t)e) = make_float4(ev[0], ev[1], ev[2], ev[3]);
}

// ---------------------------------------------------------------------------
// Aggregation: heads summed in registers -> ONE atomic per (edge,f)
// ---------------------------------------------------------------------------
template<int F, int EPB>
__global__ __launch_bounds__(EPB * F) void aggregate_kernel(
    const int* __restrict__ ei,
    const float* __restrict__ proj,
    const float* __restrict__ ex, const float* __restrict__ denom,
    float* __restrict__ agg, int softmax_on_src)
{
    int tid = threadIdx.x;
    int le  = tid / F, f = tid - le * F;
    int e   = blockIdx.x * EPB + le;
    if (e >= NE) return;
    int s = ei[e], t = ei[NE + e];
    int g = softmax_on_src ? s : t;
    const float4 ev = *(const float4*)(ex    + 4 * (size_t)e);
    const float4 dv = *(const float4*)(denom + 4 * (size_t)g);
    float a0 = ev.x / (dv.x + 1e-16f);
    float a1 = ev.y / (dv.y + 1e-16f);
    float a2 = ev.z / (dv.z + 1e-16f);
    float a3 = ev.w / (dv.w + 1e-16f);
    const float* p = proj + (size_t)s * (4 * F) + f;
    float val = p[0] * a0 + p[F] * a1 + p[2 * F] * a2 + p[3 * F] * a3;
    atomicAdd(&agg[(size_t)t * F + f], val);
}

// ---------------------------------------------------------------------------
// Finalize: aggb = bf16(agg/H + x_pb + bias)  -> feeds reproj GEMM
// ---------------------------------------------------------------------------
template<int F>
__global__ __launch_bounds__(256) void finalize_kernel(
    const float* __restrict__ agg, const short* __restrict__ x_pb,
    const float* __restrict__ bias, short* __restrict__ aggb)
{
    int i = blockIdx.x * 256 + threadIdx.x;
    if (i >= NN * F) return;
    int f = i % F;
    aggb[i] = f2b(agg[i] * 0.25f + b2f(x_pb[i]) + bias[f]);
}

// ---------------------------------------------------------------------------
extern "C" void kernel_launch(void* const* d_in, const int* in_sizes, int n_in,
                              void* d_out, int out_size, void* d_ws, size_t ws_size,
                              hipStream_t stream)
{
    const float* rna   = (const float*)d_in[0];    // [N,128]
    const float* prot  = (const float*)d_in[1];    // [N,32]
    const int*   ei    = (const int*)  d_in[2];    // [2,E]
    const float* Wgp   = (const float*)d_in[3];    // [128,64]
    const float* bgp   = (const float*)d_in[4];
    const float* Wgr   = (const float*)d_in[5];    // [64,128]
    const float* bgr   = (const float*)d_in[6];
    const float* Wg    = (const float*)d_in[7];    // [64,256]
    const float* ags   = (const float*)d_in[8];    // [4,64]
    const float* agt   = (const float*)d_in[9];
    const float* bg    = (const float*)d_in[10];   // [64]
    const float* Wcp   = (const float*)d_in[11];   // [160,96]
    const float* bcp   = (const float*)d_in[12];
    const float* Wcr   = (const float*)d_in[13];   // [96,160]
    const float* bcr   = (const float*)d_in[14];
    const float* Wc    = (const float*)d_in[15];   // [96,384]
    const float* acs   = (const float*)d_in[16];   // [4,96]
    const float* act   = (const float*)d_in[17];
    const float* bc    = (const float*)d_in[18];   // [96]

    float* out_gat   = (float*)d_out;              // [N,128]
    float* out_cross = out_gat + (size_t)NN * 128; // [N,160]

    // ---- workspace layout (≈77 MB) ----
    float* proj = (float*)d_ws;                    // N*384 f32
    float* ex   = proj + (size_t)NN * 384;         // E*4
    float* ssrc = ex   + (size_t)NE * 4;           // N*4
    float* strg = ssrc + (size_t)NN * 4;           // N*4
    float* den  = strg + (size_t)NN * 4;           // N*4
    short* cb    = (short*)(den + (size_t)NN * 4); // N*160 bf16 concat
    short* x_pb  = cb    + (size_t)NN * 160;       // N*96 bf16
    short* aggb  = x_pb  + (size_t)NN * 96;        // N*96 bf16
    short* wt_gp = aggb  + (size_t)NN * 96;        // [64,128]
    short* wt_g  = wt_gp + 128 * 64;               // [256,64]
    short* wt_gr = wt_g  + 64 * 256;               // [128,64]
    short* wt_cp = wt_gr + 64 * 128;               // [96,160]
    short* wt_c  = wt_cp + 160 * 96;               // [384,96]
    short* wt_cr = wt_c  + 96 * 384;               // [160,96]
    // agg fp32 scratch lives in the not-yet-written out_cross region (N*96 <= N*160)
    float* agg = out_cross;

    // ---- one-time converts ----
    concat_kernel<<<(NN * 40 + 255) / 256, 256, 0, stream>>>(rna, prot, cb);
    wt_kernel<<<(128 *  64 + 255) / 256, 256, 0, stream>>>(Wgp, wt_gp, 128,  64);
    wt_kernel<<<( 64 * 256 + 255) / 256, 256, 0, stream>>>(Wg,  wt_g,   64, 256);
    wt_kernel<<<( 64 * 128 + 255) / 256, 256, 0, stream>>>(Wgr, wt_gr,  64, 128);
    wt_kernel<<<(160 *  96 + 255) / 256, 256, 0, stream>>>(Wcp, wt_cp, 160,  96);
    wt_kernel<<<( 96 * 384 + 255) / 256, 256, 0, stream>>>(Wc,  wt_c,   96, 384);
    wt_kernel<<<( 96 * 160 + 255) / 256, 256, 0, stream>>>(Wcr, wt_cr,  96, 160);

    // ======================= GAT path (F=64, softmax on trg) ================
    mfma_gemm<128, 160,  64, true ><<<dim3(256,  2), 256, 0, stream>>>(cb,   wt_gp, bgp, nullptr, x_pb);
    mfma_gemm< 64,  64, 256, false><<<dim3(256,  8), 256, 0, stream>>>(x_pb, wt_g,  nullptr, proj, nullptr);
    scores_kernel<64><<<(NN * HH) / 256, 256, 0, stream>>>(proj, ags, agt, ssrc, strg);
    hipMemsetAsync(den, 0, (size_t)NN * 4 * sizeof(float), stream);
    edge_kernel<<<NE / 256, 256, 0, stream>>>(ei, ssrc, strg, ex, den, 0);
    hipMemsetAsync(agg, 0, (size_t)NN * 64 * sizeof(float), stream);
    aggregate_kernel<64, 4><<<NE / 4, 256, 0, stream>>>(ei, proj, ex, den, agg, 0);
    finalize_kernel<64><<<(NN * 64) / 256, 256, 0, stream>>>(agg, x_pb, bg, aggb);
    mfma_gemm< 64,  64, 128, false><<<dim3(256,  4), 256, 0, stream>>>(aggb, wt_gr, bgr, out_gat, nullptr);

    // ====================== Cross path (F=96, softmax on src) ===============
    mfma_gemm<160, 160,  96, true ><<<dim3(256,  3), 256, 0, stream>>>(cb,   wt_cp, bcp, nullptr, x_pb);
    mfma_gemm< 96,  96, 384, false><<<dim3(256, 12), 256, 0, stream>>>(x_pb, wt_c,  nullptr, proj, nullptr);
    scores_kernel<96><<<(NN * HH) / 256, 256, 0, stream>>>(proj, acs, act, ssrc, strg);
    hipMemsetAsync(den, 0, (size_t)NN * 4 * sizeof(float), stream);
    edge_kernel<<<NE / 256, 256, 0, stream>>>(ei, ssrc, strg, ex, den, 1);
    hipMemsetAsync(agg, 0, (size_t)NN * 96 * sizeof(float), stream);
    aggregate_kernel<96, 2><<<NE / 2, 192, 0, stream>>>(ei, proj, ex, den, agg, 1);
    finalize_kernel<96><<<(NN * 96) / 256, 256, 0, stream>>>(agg, x_pb, bc, aggb);
    mfma_gemm< 96,  96, 160, false><<<dim3(256,  5), 256, 0, stream>>>(aggb, wt_cr, bcr, out_cross, nullptr);
}

// Round 3
// 272.751 us; speedup vs baseline: 1.5459x; 1.0234x over previous
//
#include <hip/hip_runtime.h>
#include <hip/hip_bf16.h>

#define NN 32768      // nodes
#define NE 131072     // edges
#define HH 4          // heads

constexpr float kLrelu = 0.2f;

using bf16x8 = __attribute__((ext_vector_type(8))) __bf16;
using f32x4  = __attribute__((ext_vector_type(4))) float;

__device__ inline short f2b(float f) {
    __hip_bfloat16 h = __float2bfloat16(f);          // RTNE
    return __builtin_bit_cast(short, h);
}
__device__ inline float b2f(short s) {
    __hip_bfloat16 h = __builtin_bit_cast(__hip_bfloat16, s);
    return __bfloat162float(h);
}

// ---------------------------------------------------------------------------
// bf16 MFMA GEMM: C[M,OUTN] = A[M,K](bf16, row stride LDA) @ Wt^T (+bias)
// Wt is [OUTN,K] bf16. Fragments direct-from-global (m89-verified C/D layout:
// row=(lane>>4)*4+j, col=lane&15). Block = 4 waves, 128 rows x 32 cols.
// SCORES: also atomicAdd per-row partial dots with a_src/a_trg (f32 accs),
// valid because each 32-col block lies inside one head (FH % 32 == 0 cases:
// 64,96 -> col blocks 2,3 per head).
// ---------------------------------------------------------------------------
template<int K, int LDA, int OUTN, bool BF16OUT, bool SCORES, int FH>
__global__ __launch_bounds__(256) void mfma_gemm(
    const short* __restrict__ A, const short* __restrict__ Wt,
    const float* __restrict__ bias,
    float* __restrict__ Cf, short* __restrict__ Cb,
    const float* __restrict__ a_src, const float* __restrict__ a_trg,
    float* __restrict__ ssrc, float* __restrict__ strg)
{
    const int wave = threadIdx.x >> 6;
    const int lane = threadIdx.x & 63;
    const int row0 = blockIdx.x * 128 + wave * 32;
    const int col0 = blockIdx.y * 32;
    const int lr   = lane & 15;
    const int kb   = lane >> 4;            // 0..3

    f32x4 acc[2][2] = {};
    const short* a0 = A  + (size_t)(row0 + lr) * LDA + 8 * kb;
    const short* a1 = a0 + 16 * LDA;
    const short* b0 = Wt + (size_t)(col0 + lr) * K + 8 * kb;
    const short* b1 = b0 + 16 * K;

    #pragma unroll
    for (int k0 = 0; k0 < K; k0 += 32) {
        bf16x8 af0 = *(const bf16x8*)(a0 + k0);
        bf16x8 af1 = *(const bf16x8*)(a1 + k0);
        bf16x8 bv0 = *(const bf16x8*)(b0 + k0);
        bf16x8 bv1 = *(const bf16x8*)(b1 + k0);
        acc[0][0] = __builtin_amdgcn_mfma_f32_16x16x32_bf16(af0, bv0, acc[0][0], 0, 0, 0);
        acc[0][1] = __builtin_amdgcn_mfma_f32_16x16x32_bf16(af0, bv1, acc[0][1], 0, 0, 0);
        acc[1][0] = __builtin_amdgcn_mfma_f32_16x16x32_bf16(af1, bv0, acc[1][0], 0, 0, 0);
        acc[1][1] = __builtin_amdgcn_mfma_f32_16x16x32_bf16(af1, bv1, acc[1][1], 0, 0, 0);
    }

    // ---- C write ----
    #pragma unroll
    for (int mf = 0; mf < 2; ++mf) {
        #pragma unroll
        for (int nf = 0; nf < 2; ++nf) {
            const int c  = col0 + nf * 16 + lr;
            const float bv = bias ? bias[c] : 0.0f;
            #pragma unroll
            for (int j = 0; j < 4; ++j) {
                const int r = row0 + mf * 16 + kb * 4 + j;
                const float v = acc[mf][nf][j] + bv;
                if constexpr (BF16OUT) Cb[(size_t)r * OUTN + c] = f2b(v);
                else                   Cf[(size_t)r * OUTN + c] = v;
            }
        }
    }

    // ---- fused attention-score partials (f32 precision) ----
    if constexpr (SCORES) {
        const int h   = col0 / FH;
        const int cf0 = col0 - h * FH;
        const float as0 = a_src[h * FH + cf0 + lr];
        const float as1 = a_src[h * FH + cf0 + 16 + lr];
        const float at0 = a_trg[h * FH + cf0 + lr];
        const float at1 = a_trg[h * FH + cf0 + 16 + lr];
        #pragma unroll
        for (int mf = 0; mf < 2; ++mf) {
            #pragma unroll
            for (int j = 0; j < 4; ++j) {
                float ps = acc[mf][0][j] * as0 + acc[mf][1][j] * as1;
                float pt = acc[mf][0][j] * at0 + acc[mf][1][j] * at1;
                #pragma unroll
                for (int m = 1; m < 16; m <<= 1) {
                    ps += __shfl_xor(ps, m);
                    pt += __shfl_xor(pt, m);
                }
                if (lr == 0) {
                    const int r = row0 + mf * 16 + kb * 4 + j;
                    atomicAdd(&ssrc[r * HH + h], ps);
                    atomicAdd(&strg[r * HH + h], pt);
                }
            }
        }
    }
}

// ---------------------------------------------------------------------------
// All 6 weight transposes (fp32 -> bf16, [K,N] -> [N,K]) in one launch.
// ---------------------------------------------------------------------------
__global__ __launch_bounds__(256) void wt_all_kernel(
    const float* W0, const float* W1, const float* W2,
    const float* W3, const float* W4, const float* W5,
    short* T0, short* T1, short* T2, short* T3, short* T4, short* T5)
{
    int K, N; const float* W; short* T;
    switch (blockIdx.y) {
        case 0: K = 128; N =  64; W = W0; T = T0; break;
        case 1: K =  64; N = 256; W = W1; T = T1; break;
        case 2: K =  64; N = 128; W = W2; T = T2; break;
        case 3: K = 160; N =  96; W = W3; T = T3; break;
        case 4: K =  96; N = 384; W = W4; T = T4; break;
        default:K =  96; N = 160; W = W5; T = T5; break;
    }
    int t = blockIdx.x * 256 + threadIdx.x;
    if (t >= K * N) return;
    int n = t / K, k = t - n * K;
    T[t] = f2b(W[(size_t)k * N + n]);
}

// ---------------------------------------------------------------------------
// Build bf16 concat [N,160] = [rna | prot]
// ---------------------------------------------------------------------------
__global__ __launch_bounds__(256) void concat_kernel(
    const float* __restrict__ rna, const float* __restrict__ prot,
    short* __restrict__ cb)
{
    int t = blockIdx.x * 256 + threadIdx.x;
    if (t >= NN * 40) return;
    int n = t / 40, j = (t - n * 40) * 4;
    float4 v = (j < 128) ? *(const float4*)(rna  + (size_t)n * 128 + j)
                         : *(const float4*)(prot + (size_t)n * 32 + (j - 128));
    short4 o = { f2b(v.x), f2b(v.y), f2b(v.z), f2b(v.w) };
    *(short4*)(cb + (size_t)n * 160 + j) = o;
}

// ---------------------------------------------------------------------------
// CSR build (grouped by trg, shared by both paths)
// ---------------------------------------------------------------------------
__global__ __launch_bounds__(256) void hist_kernel(const int* __restrict__ ei,
                                                   int* __restrict__ deg)
{
    int e = blockIdx.x * 256 + threadIdx.x;
    if (e < NE) atomicAdd(&deg[ei[NE + e]], 1);
}

__global__ __launch_bounds__(1024) void scan_kernel(const int* __restrict__ deg,
                                                    int* __restrict__ rowptr,
                                                    int* __restrict__ cursor)
{
    __shared__ int sums[1024];
    const int t = threadIdx.x;
    const int base = t * 32;
    int local[32];
    int s = 0;
    #pragma unroll
    for (int i = 0; i < 32; ++i) { local[i] = s; s += deg[base + i]; }
    sums[t] = s;
    __syncthreads();
    for (int off = 1; off < 1024; off <<= 1) {
        int v = (t >= off) ? sums[t - off] : 0;
        __syncthreads();
        sums[t] += v;
        __syncthreads();
    }
    const int prev = (t == 0) ? 0 : sums[t - 1];
    #pragma unroll
    for (int i = 0; i < 32; ++i) {
        rowptr[base + i] = prev + local[i];
        cursor[base + i] = prev + local[i];
    }
    if (t == 1023) rowptr[NN] = prev + s;
}

__global__ __launch_bounds__(256) void scatter_kernel(
    const int* __restrict__ ei, int* __restrict__ cursor,
    int* __restrict__ csr_src, int* __restrict__ csr_e)
{
    int e = blockIdx.x * 256 + threadIdx.x;
    if (e >= NE) return;
    int s = ei[e], t = ei[NE + e];
    int slot = atomicAdd(&cursor[t], 1);
    csr_src[slot] = s;
    csr_e[slot]   = e;
}

// ---------------------------------------------------------------------------
// Per-edge exp(lrelu(score)); denom atomics only for the src-grouped path.
// ---------------------------------------------------------------------------
template<bool DENOM>
__global__ __launch_bounds__(256) void edge_kernel(
    const int* __restrict__ ei,
    const float* __restrict__ s_src, const float* __restrict__ s_trg,
    float* __restrict__ ex, float* __restrict__ denom)
{
    int e = blockIdx.x * 256 + threadIdx.x;
    if (e >= NE) return;
    int s = ei[e], t = ei[NE + e];
    const float4 ss = *(const float4*)(s_src + 4 * (size_t)s);
    const float4 st = *(const float4*)(s_trg + 4 * (size_t)t);
    float sc[4] = { ss.x + st.x, ss.y + st.y, ss.z + st.z, ss.w + st.w };
    float ev[4];
    #pragma unroll
    for (int h = 0; h < 4; ++h) {
        float x  = sc[h];
        float lr = x > 0.f ? x : kLrelu * x;
        ev[h] = expf(lr);
        if constexpr (DENOM) atomicAdd(&denom[4 * (size_t)s + h], ev[h]);
    }
    *(float4*)(ex + 4 * (size_t)e) = make_float4(ev[0], ev[1], ev[2], ev[3]);
}

// ---------------------------------------------------------------------------
// CSR aggregation, atomic-free output, fused mean+skip+bias -> bf16.
// GROUP_SRC=false (GAT): softmax group == trg -> denominator in-kernel.
// GROUP_SRC=true (cross): denominators gathered from den[src].
// blockDim = (F, NPB); thread = (feature f, local node).
// ---------------------------------------------------------------------------
template<int F, int NPB, bool GROUP_SRC>
__global__ __launch_bounds__(F * NPB) void aggregate_csr(
    const int* __restrict__ rowptr, const int* __restrict__ csr_src,
    const int* __restrict__ csr_e,
    const short* __restrict__ proj_b, const float* __restrict__ ex,
    const float* __restrict__ den,
    const short* __restrict__ x_pb, const float* __restrict__ bias,
    short* __restrict__ aggb)
{
    const int f    = threadIdx.x;
    const int node = blockIdx.x * NPB + threadIdx.y;
    const int beg  = rowptr[node], end = rowptr[node + 1];
    float acc = 0.f;

    if constexpr (!GROUP_SRC) {
        float d0 = 0.f, d1 = 0.f, d2 = 0.f, d3 = 0.f;
        for (int sl = beg; sl < end; ++sl) {
            const float4 ev = *(const float4*)(ex + 4 * (size_t)csr_e[sl]);
            d0 += ev.x; d1 += ev.y; d2 += ev.z; d3 += ev.w;
        }
        const float r0 = 1.f / (d0 + 1e-16f), r1 = 1.f / (d1 + 1e-16f);
        const float r2 = 1.f / (d2 + 1e-16f), r3 = 1.f / (d3 + 1e-16f);
        for (int sl = beg; sl < end; ++sl) {
            const int s = csr_src[sl];
            const float4 ev = *(const float4*)(ex + 4 * (size_t)csr_e[sl]);
            const short* p = proj_b + (size_t)s * (4 * F) + f;
            acc += b2f(p[0])     * (ev.x * r0) + b2f(p[F])     * (ev.y * r1)
                 + b2f(p[2 * F]) * (ev.z * r2) + b2f(p[3 * F]) * (ev.w * r3);
        }
    } else {
        for (int sl = beg; sl < end; ++sl) {
            const int s = csr_src[sl];
            const float4 ev = *(const float4*)(ex  + 4 * (size_t)csr_e[sl]);
            const float4 dv = *(const float4*)(den + 4 * (size_t)s);
            const short* p = proj_b + (size_t)s * (4 * F) + f;
            acc += b2f(p[0])     * (ev.x / (dv.x + 1e-16f))
                 + b2f(p[F])     * (ev.y / (dv.y + 1e-16f))
                 + b2f(p[2 * F]) * (ev.z / (dv.z + 1e-16f))
                 + b2f(p[3 * F]) * (ev.w / (dv.w + 1e-16f));
        }
    }
    const int o = node * F + f;
    aggb[o] = f2b(acc * 0.25f + b2f(x_pb[o]) + bias[f]);
}

// ---------------------------------------------------------------------------
extern "C" void kernel_launch(void* const* d_in, const int* in_sizes, int n_in,
                              void* d_out, int out_size, void* d_ws, size_t ws_size,
                              hipStream_t stream)
{
    const float* rna   = (const float*)d_in[0];    // [N,128]
    const float* prot  = (const float*)d_in[1];    // [N,32]
    const int*   ei    = (const int*)  d_in[2];    // [2,E]
    const float* Wgp   = (const float*)d_in[3];    // [128,64]
    const float* bgp   = (const float*)d_in[4];
    const float* Wgr   = (const float*)d_in[5];    // [64,128]
    const float* bgr   = (const float*)d_in[6];
    const float* Wg    = (const float*)d_in[7];    // [64,256]
    const float* ags   = (const float*)d_in[8];    // [4,64]
    const float* agt   = (const float*)d_in[9];
    const float* bg    = (const float*)d_in[10];   // [64]
    const float* Wcp   = (const float*)d_in[11];   // [160,96]
    const float* bcp   = (const float*)d_in[12];
    const float* Wcr   = (const float*)d_in[13];   // [96,160]
    const float* bcr   = (const float*)d_in[14];
    const float* Wc    = (const float*)d_in[15];   // [96,384]
    const float* acs   = (const float*)d_in[16];   // [4,96]
    const float* act   = (const float*)d_in[17];
    const float* bc    = (const float*)d_in[18];   // [96]

    float* out_gat   = (float*)d_out;              // [N,128]
    float* out_cross = out_gat + (size_t)NN * 128; // [N,160]

    // ---- workspace layout ----
    float* ex    = (float*)d_ws;                   // E*4 f32
    float* ssrc  = ex   + (size_t)NE * 4;          // N*4 f32
    float* strg  = ssrc + (size_t)NN * 4;          // N*4 f32
    float* den   = strg + (size_t)NN * 4;          // N*4 f32
    short* proj_b = (short*)(den + (size_t)NN * 4);// N*384 bf16
    short* cb    = proj_b + (size_t)NN * 384;      // N*160 bf16
    short* x_pb  = cb    + (size_t)NN * 160;       // N*96 bf16
    short* aggb  = x_pb  + (size_t)NN * 96;        // N*96 bf16
    short* wt_gp = aggb  + (size_t)NN * 96;        // [64,128]
    short* wt_g  = wt_gp + 128 * 64;               // [256,64]
    short* wt_gr = wt_g  + 64 * 256;               // [128,64]
    short* wt_cp = wt_gr + 64 * 128;               // [96,160]
    short* wt_c  = wt_cp + 160 * 96;               // [384,96]
    short* wt_cr = wt_c  + 96 * 384;               // [160,96]
    int*   deg   = (int*)(wt_cr + 96 * 160);       // N
    int*   cursor= deg    + NN;                    // N
    int*   rowptr= cursor + NN;                    // N+1
    int*   csr_src = rowptr + NN + 1;              // E
    int*   csr_e   = csr_src + NE;                 // E

    // ---- one-time converts + CSR build (shared by both paths) ----
    concat_kernel<<<(NN * 40 + 255) / 256, 256, 0, stream>>>(rna, prot, cb);
    wt_all_kernel<<<dim3(144, 6), 256, 0, stream>>>(Wgp, Wg, Wgr, Wcp, Wc, Wcr,
                                                    wt_gp, wt_g, wt_gr, wt_cp, wt_c, wt_cr);
    hipMemsetAsync(deg, 0, (size_t)NN * sizeof(int), stream);
    hist_kernel<<<NE / 256, 256, 0, stream>>>(ei, deg);
    scan_kernel<<<1, 1024, 0, stream>>>(deg, rowptr, cursor);
    scatter_kernel<<<NE / 256, 256, 0, stream>>>(ei, cursor, csr_src, csr_e);

    // ======================= GAT path (F=64, softmax on trg) ================
    hipMemsetAsync(ssrc, 0, (size_t)NN * 12 * sizeof(float), stream);  // ssrc+strg+den
    mfma_gemm<128, 160,  64, true , false,  64><<<dim3(256, 2), 256, 0, stream>>>(
        cb, wt_gp, bgp, nullptr, x_pb, nullptr, nullptr, nullptr, nullptr);
    mfma_gemm< 64,  64, 256, true , true ,  64><<<dim3(256, 8), 256, 0, stream>>>(
        x_pb, wt_g, nullptr, nullptr, proj_b, ags, agt, ssrc, strg);
    edge_kernel<false><<<NE / 256, 256, 0, stream>>>(ei, ssrc, strg, ex, den);
    aggregate_csr<64, 4, false><<<NN / 4, dim3(64, 4), 0, stream>>>(
        rowptr, csr_src, csr_e, proj_b, ex, nullptr, x_pb, bg, aggb);
    mfma_gemm< 64,  64, 128, false, false,  64><<<dim3(256, 4), 256, 0, stream>>>(
        aggb, wt_gr, bgr, out_gat, nullptr, nullptr, nullptr, nullptr, nullptr);

    // ====================== Cross path (F=96, softmax on src) ===============
    hipMemsetAsync(ssrc, 0, (size_t)NN * 12 * sizeof(float), stream);  // ssrc+strg+den
    mfma_gemm<160, 160,  96, true , false,  96><<<dim3(256, 3), 256, 0, stream>>>(
        cb, wt_cp, bcp, nullptr, x_pb, nullptr, nullptr, nullptr, nullptr);
    mfma_gemm< 96,  96, 384, true , true ,  96><<<dim3(256, 12), 256, 0, stream>>>(
        x_pb, wt_c, nullptr, nullptr, proj_b, acs, act, ssrc, strg);
    edge_kernel<true><<<NE / 256, 256, 0, stream>>>(ei, ssrc, strg, ex, den);
    aggregate_csr<96, 2, true><<<NN / 2, dim3(96, 2), 0, stream>>>(
        rowptr, csr_src, csr_e, proj_b, ex, den, x_pb, bc, aggb);
    mfma_gemm< 96,  96, 160, false, false,  96><<<dim3(256, 5), 256, 0, stream>>>(
        aggb, wt_cr, bcr, out_cross, nullptr, nullptr, nullptr, nullptr, nullptr);
}